// Round 10
// baseline (893.837 us; speedup 1.0000x reference)
//
#include <hip/hip_runtime.h>
#include <stdint.h>
#include <math.h>

typedef unsigned short ushort_t;
typedef __bf16 bf16x8 __attribute__((ext_vector_type(8)));
typedef unsigned short ushx8 __attribute__((ext_vector_type(8)));
typedef float f32x4 __attribute__((ext_vector_type(4)));

#define DEV static __device__ __forceinline__

DEV float bf2f(ushort_t h) {
    union { unsigned u; float f; } v;
    v.u = ((unsigned)h) << 16;
    return v.f;
}
DEV ushort_t f2bf(float f) {
    union { float f; unsigned u; } v;
    v.f = f;
    unsigned r = v.u + 0x7fffu + ((v.u >> 16) & 1u);
    return (ushort_t)(r >> 16);
}
// runtime-dtype input read (flat element index): flag -> fp32, else bf16 bits
DEV float ldin(const void* p, size_t i, int isf32) {
    return isf32 ? ((const float*)p)[i] : bf2f(((const ushort_t*)p)[i]);
}
DEV bf16x8 ldfrag(const ushort_t* p) {
    return __builtin_bit_cast(bf16x8, *(const ushx8*)p);
}
// async global->LDS, 16 B per lane; LDS dest = wave-uniform base + lane*16
DEV void gld16(const ushort_t* g, ushort_t* l) {
    __builtin_amdgcn_global_load_lds((const __attribute__((address_space(1))) void*)g,
                                     (__attribute__((address_space(3))) void*)l, 16, 0, 0);
}

// ---------------- dtype detector: writes 1 if inputs are fp32 ----------------
__global__ __launch_bounds__(256) void detect_kernel(const ushort_t* __restrict__ x,
                                                     int* __restrict__ flag) {
    __shared__ int bad;
    if (threadIdx.x == 0) bad = 0;
    __syncthreads();
    int b = 0;
#pragma unroll
    for (int i = 0; i < 8; ++i) {
        float v = fabsf(bf2f(x[threadIdx.x * 8 + i]));
        if (!(v <= 16384.f)) b = 1;  // catches huge exponents AND NaN
    }
    if (b) atomicOr(&bad, 1);
    __syncthreads();
    if (threadIdx.x == 0) *flag = bad;
}

// ---------------- per-layer weight pack: W[k][n] -> WT[n][k] bf16, biases -> fp32 ----
__global__ __launch_bounds__(256) void pack_kernel(const void* __restrict__ Wq, const void* __restrict__ Wk,
                                                   const void* __restrict__ Wv, const void* __restrict__ Wo,
                                                   const void* __restrict__ W1, const void* __restrict__ W2,
                                                   const void* __restrict__ bq, const void* __restrict__ bk,
                                                   const void* __restrict__ bv, const void* __restrict__ bo,
                                                   const void* __restrict__ b1, const void* __restrict__ b2,
                                                   size_t wD, size_t wF, size_t bD, size_t bF,
                                                   ushort_t* __restrict__ WqkvT, ushort_t* __restrict__ WoT,
                                                   ushort_t* __restrict__ W1T, ushort_t* __restrict__ W2T,
                                                   float* __restrict__ biasbuf,
                                                   const int* __restrict__ flag) {
    const int isf32 = *flag;
    const int id = blockIdx.x, tid = threadIdx.x;
    if (id < 3072) {
        __shared__ ushort_t T[32][33];
        const void* src;
        size_t soff;
        int srcN, dstK, n0, k0;
        ushort_t* dst;
        if (id < 768) {          // QKV -> WqkvT[1536][512]
            int nt = id >> 4, kt = id & 15;
            int qkv = nt >> 4;
            src = qkv == 0 ? Wq : (qkv == 1 ? Wk : Wv);
            soff = wD; srcN = 512; dstK = 512;
            dst = WqkvT + (size_t)(qkv * 512) * 512;
            n0 = (nt & 15) * 32; k0 = kt * 32;
        } else if (id < 1024) {  // Wo -> WoT[512][512]
            int t = id - 768; int nt = t >> 4, kt = t & 15;
            src = Wo; soff = wD; srcN = 512; dst = WoT; dstK = 512;
            n0 = nt * 32; k0 = kt * 32;
        } else if (id < 2048) {  // W1[512][2048] -> W1T[2048][512]
            int t = id - 1024; int nt = t >> 4, kt = t & 15;
            src = W1; soff = wF; srcN = 2048; dst = W1T; dstK = 512;
            n0 = nt * 32; k0 = kt * 32;
        } else {                 // W2[2048][512] -> W2T[512][2048]
            int t = id - 2048; int nt = t >> 6, kt = t & 63;
            src = W2; soff = wF; srcN = 512; dst = W2T; dstK = 2048;
            n0 = nt * 32; k0 = kt * 32;
        }
        const int col = tid & 31, rw = tid >> 5;
#pragma unroll
        for (int p = 0; p < 4; ++p) {
            int kk = rw + p * 8;
            T[kk][col] = f2bf(ldin(src, soff + (size_t)(k0 + kk) * srcN + n0 + col, isf32));
        }
        __syncthreads();
#pragma unroll
        for (int p = 0; p < 4; ++p) {
            int nn = rw + p * 8;
            dst[(size_t)(n0 + nn) * dstK + k0 + col] = T[col][nn];
        }
    } else {
        int j = (id - 3072) * 256 + tid;  // 0..4607: [bq|bk|bv|bo|b1|b2]
        float v;
        if (j < 512) v = ldin(bq, bD + j, isf32);
        else if (j < 1024) v = ldin(bk, bD + j - 512, isf32);
        else if (j < 1536) v = ldin(bv, bD + j - 1024, isf32);
        else if (j < 2048) v = ldin(bo, bD + j - 1536, isf32);
        else if (j < 4096) v = ldin(b1, bF + j - 2048, isf32);
        else v = ldin(b2, bD + j - 4096, isf32);
        biasbuf[j] = v;
    }
}

// ---------------- PE add: X(bf16) = x + pos_encoding ----------------
__global__ __launch_bounds__(256) void pe_kernel(const void* __restrict__ x,
                                                 ushort_t* __restrict__ X,
                                                 const int* __restrict__ flag) {
    const int isf32 = *flag;
    int i = blockIdx.x * 256 + threadIdx.x;
    int d = i & 511;
    int s = (i >> 9) & 1023;
    float freq = expf((float)(d & ~1) * (-9.210340371976184f / 512.f));
    float ang = (float)s * freq;
    float pe = (d & 1) ? cosf(ang) : sinf(ang);
    X[i] = f2bf(ldin(x, i, isf32) + pe);
}

// ---------------- MFMA bf16 GEMM (m97 structure, optional K-split over z) ----------
template <typename CT, bool RELU>
__global__ __launch_bounds__(256) void gemm2_kernel(const ushort_t* __restrict__ A,
                                                    const ushort_t* __restrict__ Bp,
                                                    const float* __restrict__ bias,
                                                    CT* __restrict__ C0, CT* __restrict__ C1,
                                                    int M, int K, int N, int kSplit) {
    __shared__ ushort_t As[128 * 32];
    __shared__ ushort_t Bs[128 * 32];
    const int tid = threadIdx.x;
    const int bm = blockIdx.y * 128;
    const int bn = blockIdx.x * 128;
    const int z = blockIdx.z;
    const int kBeg = z * kSplit, kEnd = kBeg + kSplit;
    CT* C = z ? C1 : C0;
    const int w = tid >> 6, lane = tid & 63;
    const int wm = (w >> 1) * 64, wn = (w & 1) * 64;

    f32x4 acc[4][4];
#pragma unroll
    for (int i = 0; i < 4; ++i)
#pragma unroll
        for (int j = 0; j < 4; ++j) acc[i][j] = (f32x4){0.f, 0.f, 0.f, 0.f};

    const int srow = tid >> 2;
    const int sko = (tid & 3) * 8;
    const ushort_t* a0 = A + (size_t)(bm + srow) * K + sko;
    const ushort_t* a1 = A + (size_t)(bm + 64 + srow) * K + sko;
    const ushort_t* b0 = Bp + (size_t)(bn + srow) * K + sko;
    const ushort_t* b1 = Bp + (size_t)(bn + 64 + srow) * K + sko;
    ushort_t* lA0 = As + tid * 8;
    ushort_t* lA1 = As + 2048 + tid * 8;
    ushort_t* lB0 = Bs + tid * 8;
    ushort_t* lB1 = Bs + 2048 + tid * 8;

    const int fm = lane & 15;
    const int fk = (lane >> 4) * 8;

    for (int k0 = kBeg; k0 < kEnd; k0 += 32) {
        gld16(a0 + k0, lA0);
        gld16(a1 + k0, lA1);
        gld16(b0 + k0, lB0);
        gld16(b1 + k0, lB1);
        __syncthreads();
        bf16x8 af[4], bfr[4];
#pragma unroll
        for (int i = 0; i < 4; ++i)
            af[i] = ldfrag(&As[(wm + i * 16 + fm) * 32 + fk]);
#pragma unroll
        for (int j = 0; j < 4; ++j)
            bfr[j] = ldfrag(&Bs[(wn + j * 16 + fm) * 32 + fk]);
#pragma unroll
        for (int i = 0; i < 4; ++i)
#pragma unroll
            for (int j = 0; j < 4; ++j)
                acc[i][j] = __builtin_amdgcn_mfma_f32_16x16x32_bf16(af[i], bfr[j], acc[i][j], 0, 0, 0);
        __syncthreads();
    }
    const int cn = lane & 15;
    const int rq = (lane >> 4) * 4;
    if constexpr (sizeof(CT) == 2) {
        __shared__ ushort_t Ep[4][64 * 72];
#pragma unroll
        for (int j = 0; j < 4; ++j) {
            const float bv = z ? 0.f : bias[bn + wn + j * 16 + cn];
#pragma unroll
            for (int i = 0; i < 4; ++i) {
#pragma unroll
                for (int r = 0; r < 4; ++r) {
                    float v = acc[i][j][r] + bv;
                    if constexpr (RELU) v = fmaxf(v, 0.f);
                    Ep[w][(i * 16 + rq + r) * 72 + j * 16 + cn] = f2bf(v);
                }
            }
        }
        const int rr = lane >> 3, cc = (lane & 7) * 8;
#pragma unroll
        for (int g = 0; g < 8; ++g) {
            const int row = g * 8 + rr;
            *(ushx8*)((ushort_t*)C + (size_t)(bm + wm + row) * N + bn + wn + cc) =
                *(const ushx8*)&Ep[w][row * 72 + cc];
        }
    } else {
#pragma unroll
        for (int j = 0; j < 4; ++j) {
            const int n = bn + wn + j * 16 + cn;
            const float bv = z ? 0.f : bias[n];
#pragma unroll
            for (int i = 0; i < 4; ++i) {
#pragma unroll
                for (int r = 0; r < 4; ++r) {
                    const int m = bm + wm + i * 16 + rq + r;
                    float v = acc[i][j][r] + bv;
                    if constexpr (RELU) v = fmaxf(v, 0.f);
                    ((float*)C)[(size_t)m * N + n] = v;
                }
            }
        }
    }
}

// ---------------- V transpose via LDS: VT[b][h][d][s], coalesced both ways --------
__global__ __launch_bounds__(256) void vt_kernel(const ushort_t* __restrict__ QKV,
                                                 ushort_t* __restrict__ VT) {
    __shared__ ushort_t T[64][72];
    const int st = blockIdx.x, h = blockIdx.y, b = blockIdx.z;
    const int tid = threadIdx.x;
    const int s = tid & 63;
    const int dc = (tid >> 6) * 16;
    const ushort_t* src = QKV + ((size_t)b * 1024 + st * 64 + s) * 1536 + 1024 + h * 64 + dc;
    ushx8 r0 = *(const ushx8*)src;
    ushx8 r1 = *(const ushx8*)(src + 8);
#pragma unroll
    for (int i = 0; i < 8; ++i) T[dc + i][s] = r0[i];
#pragma unroll
    for (int i = 0; i < 8; ++i) T[dc + 8 + i][s] = r1[i];
    __syncthreads();
    const int d = tid >> 2;
    const int sc = (tid & 3) * 16;
    ushort_t* dst = VT + (((size_t)(b * 8 + h)) * 64 + d) * 1024 + st * 64 + sc;
    *(ushx8*)dst = *(const ushx8*)&T[d][sc];
    *(ushx8*)(dst + 8) = *(const ushx8*)&T[d][sc + 8];
}

// ---------------- Flash attention: block = (b,h,128-q tile), 2 strips/wave ----------
// QKV rows of 1536 (Q|K|V). VT[b][h][d][s]. O row stride 512. XOR-swizzled LDS.
__global__ __launch_bounds__(256) void fattn_kernel(const ushort_t* __restrict__ QKV,
                                                    const ushort_t* __restrict__ VT,
                                                    const int* __restrict__ lens,
                                                    ushort_t* __restrict__ O) {
    __shared__ ushort_t Qs[128 * 64];  // 16 KB, two 64-row strips
    __shared__ ushort_t Ks[64 * 64];
    __shared__ ushort_t Vs[64 * 64];   // [d][key]
    __shared__ ushort_t Ps[128 * 72];  // padded; wave-private strips
    const int qt = blockIdx.x, h = blockIdx.y, b = blockIdx.z;
    const int tid = threadIdx.x, w = tid >> 6, L = tid & 63;
    const int len = lens[b];
    const size_t qkvb = ((size_t)b * 1024) * 1536 + (size_t)h * 64;
    const size_t vtb = ((size_t)(b * 8 + h)) * 64 * 1024;
    const int fm = L & 15, q4 = L >> 4;
    const int cl = L & 15, rq = (L >> 4) * 4;
    const int sr = tid >> 3;
    const int gch = (tid & 7) ^ (sr & 7);
    const int sw = fm & 7;

#pragma unroll
    for (int qs = 0; qs < 4; ++qs)
        gld16(QKV + qkvb + (size_t)(qt * 128 + qs * 32 + sr) * 1536 + gch * 8,
              Qs + qs * 2048 + tid * 8);

    float rs[2][4] = {{0.f, 0.f, 0.f, 0.f}, {0.f, 0.f, 0.f, 0.f}};
    f32x4 oacc[2][4];
#pragma unroll
    for (int s2 = 0; s2 < 2; ++s2)
#pragma unroll
        for (int dt = 0; dt < 4; ++dt) oacc[s2][dt] = (f32x4){0.f, 0.f, 0.f, 0.f};
    const float sscale = 0.125f * 1.44269504f;

    const int nkb = (len + 63) >> 6;
    for (int kb = 0; kb < nkb; ++kb) {
        __syncthreads();
        gld16(QKV + qkvb + 512 + (size_t)(kb * 64 + sr) * 1536 + gch * 8, Ks + tid * 8);
        gld16(QKV + qkvb + 512 + (size_t)(kb * 64 + 32 + sr) * 1536 + gch * 8, Ks + 2048 + tid * 8);
        gld16(VT + vtb + (size_t)sr * 1024 + kb * 64 + gch * 8, Vs + tid * 8);
        gld16(VT + vtb + (size_t)(32 + sr) * 1024 + kb * 64 + gch * 8, Vs + 2048 + tid * 8);
        __syncthreads();
        const int colb = kb * 64;
#pragma unroll
        for (int s2 = 0; s2 < 2; ++s2) {
            const int qrow = s2 * 64 + w * 16;
            f32x4 sacc[4];
#pragma unroll
            for (int j = 0; j < 4; ++j) sacc[j] = (f32x4){0.f, 0.f, 0.f, 0.f};
#pragma unroll
            for (int st = 0; st < 2; ++st) {
                const int pc = ((st * 4 + q4) ^ sw) * 8;
                bf16x8 af = ldfrag(&Qs[(qrow + fm) * 64 + pc]);
#pragma unroll
                for (int j = 0; j < 4; ++j) {
                    bf16x8 bf = ldfrag(&Ks[(j * 16 + fm) * 64 + pc]);
                    sacc[j] = __builtin_amdgcn_mfma_f32_16x16x32_bf16(af, bf, sacc[j], 0, 0, 0);
                }
            }
#pragma unroll
            for (int j = 0; j < 4; ++j) {
                const bool mk = (colb + j * 16 + cl) >= len;
#pragma unroll
                for (int r = 0; r < 4; ++r) {
                    float p = mk ? 0.f : exp2f(sacc[j][r] * sscale);
                    sacc[j][r] = p;
                    rs[s2][r] += p;
                }
            }
#pragma unroll
            for (int j = 0; j < 4; ++j)
#pragma unroll
                for (int r = 0; r < 4; ++r)
                    Ps[(qrow + rq + r) * 72 + j * 16 + cl] = f2bf(sacc[j][r]);
#pragma unroll
            for (int st = 0; st < 2; ++st) {
                const int pc = ((st * 4 + q4) ^ sw) * 8;
                bf16x8 pf = ldfrag(&Ps[(qrow + fm) * 72 + st * 32 + q4 * 8]);
#pragma unroll
                for (int dt = 0; dt < 4; ++dt) {
                    bf16x8 vf = ldfrag(&Vs[(dt * 16 + fm) * 64 + pc]);
                    oacc[s2][dt] = __builtin_amdgcn_mfma_f32_16x16x32_bf16(pf, vf, oacc[s2][dt], 0, 0, 0);
                }
            }
        }
    }
#pragma unroll
    for (int msk = 1; msk <= 8; msk <<= 1)
#pragma unroll
        for (int s2 = 0; s2 < 2; ++s2)
#pragma unroll
            for (int r = 0; r < 4; ++r) rs[s2][r] += __shfl_xor(rs[s2][r], msk);
    const size_t ob = ((size_t)b * 1024) * 512 + (size_t)h * 64;
#pragma unroll
    for (int s2 = 0; s2 < 2; ++s2) {
        float inv[4];
#pragma unroll
        for (int r = 0; r < 4; ++r) inv[r] = 1.f / rs[s2][r];
#pragma unroll
        for (int dt = 0; dt < 4; ++dt) {
#pragma unroll
            for (int r = 0; r < 4; ++r) {
                const int q = qt * 128 + s2 * 64 + w * 16 + rq + r;
                const int d = dt * 16 + cl;
                O[ob + (size_t)q * 512 + d] = f2bf(oacc[s2][dt][r] * inv[r]);
            }
        }
    }
}

// ---------------- Residual + LayerNorm (single fp32 operand) ----------------
__global__ __launch_bounds__(256) void ln_kernel(const ushort_t* __restrict__ A,
                                                 const float* __restrict__ B,
                                                 const void* __restrict__ g,
                                                 const void* __restrict__ be, size_t pOff,
                                                 ushort_t* __restrict__ out,
                                                 const int* __restrict__ flag) {
    const int isf32 = *flag;
    __shared__ float red[8];
    const int row = blockIdx.x, tid = threadIdx.x;
    const int wave = tid >> 6, lane = tid & 63;
    const size_t off = (size_t)row * 512;
    float v0 = bf2f(A[off + tid]) + B[off + tid];
    float v1 = bf2f(A[off + tid + 256]) + B[off + tid + 256];
    float s = v0 + v1;
#pragma unroll
    for (int o = 32; o; o >>= 1) s += __shfl_xor(s, o);
    if (lane == 0) red[wave] = s;
    __syncthreads();
    const float mean = (red[0] + red[1] + red[2] + red[3]) * (1.f / 512.f);
    const float d0 = v0 - mean, d1 = v1 - mean;
    float ss = d0 * d0 + d1 * d1;
#pragma unroll
    for (int o = 32; o; o >>= 1) ss += __shfl_xor(ss, o);
    if (lane == 0) red[4 + wave] = ss;
    __syncthreads();
    const float var = (red[4] + red[5] + red[6] + red[7]) * (1.f / 511.f);
    const float inv = 1.f / (sqrtf(var) + 1e-6f);
    out[off + tid] = f2bf(ldin(g, pOff + tid, isf32) * d0 * inv + ldin(be, pOff + tid, isf32));
    out[off + tid + 256] = f2bf(ldin(g, pOff + tid + 256, isf32) * d1 * inv + ldin(be, pOff + tid + 256, isf32));
}

// ---------------- Residual + LayerNorm (two fp32 operands: split-K halves) --------
__global__ __launch_bounds__(256) void ln2_kernel(const ushort_t* __restrict__ A,
                                                  const float* __restrict__ B,
                                                  const float* __restrict__ B2,
                                                  const void* __restrict__ g,
                                                  const void* __restrict__ be, size_t pOff,
                                                  ushort_t* __restrict__ out,
                                                  const int* __restrict__ flag) {
    const int isf32 = *flag;
    __shared__ float red[8];
    const int row = blockIdx.x, tid = threadIdx.x;
    const int wave = tid >> 6, lane = tid & 63;
    const size_t off = (size_t)row * 512;
    float v0 = bf2f(A[off + tid]) + B[off + tid] + B2[off + tid];
    float v1 = bf2f(A[off + tid + 256]) + B[off + tid + 256] + B2[off + tid + 256];
    float s = v0 + v1;
#pragma unroll
    for (int o = 32; o; o >>= 1) s += __shfl_xor(s, o);
    if (lane == 0) red[wave] = s;
    __syncthreads();
    const float mean = (red[0] + red[1] + red[2] + red[3]) * (1.f / 512.f);
    const float d0 = v0 - mean, d1 = v1 - mean;
    float ss = d0 * d0 + d1 * d1;
#pragma unroll
    for (int o = 32; o; o >>= 1) ss += __shfl_xor(ss, o);
    if (lane == 0) red[4 + wave] = ss;
    __syncthreads();
    const float var = (red[4] + red[5] + red[6] + red[7]) * (1.f / 511.f);
    const float inv = 1.f / (sqrtf(var) + 1e-6f);
    out[off + tid] = f2bf(ldin(g, pOff + tid, isf32) * d0 * inv + ldin(be, pOff + tid, isf32));
    out[off + tid + 256] = f2bf(ldin(g, pOff + tid + 256, isf32) * d1 * inv + ldin(be, pOff + tid + 256, isf32));
}

// ---------------- final bf16 -> output dtype ----------------
__global__ __launch_bounds__(256) void out_kernel(const ushort_t* __restrict__ X,
                                                  void* __restrict__ out,
                                                  const int* __restrict__ flag) {
    const int isf32 = *flag;
    int i = blockIdx.x * 256 + threadIdx.x;
    if (isf32)
        ((float*)out)[i] = bf2f(X[i]);
    else
        ((ushort_t*)out)[i] = X[i];
}

extern "C" void kernel_launch(void* const* d_in, const int* in_sizes, int n_in,
                              void* d_out, int out_size, void* d_ws, size_t ws_size,
                              hipStream_t stream) {
    const void* x   = d_in[0];
    const int* lens = (const int*)d_in[1];
    const void* Wq  = d_in[2];
    const void* bq  = d_in[3];
    const void* Wk  = d_in[4];
    const void* bk  = d_in[5];
    const void* Wv  = d_in[6];
    const void* bv  = d_in[7];
    const void* Wo  = d_in[8];
    const void* bo  = d_in[9];
    const void* W1  = d_in[10];
    const void* b1  = d_in[11];
    const void* W2  = d_in[12];
    const void* b2  = d_in[13];
    const void* g1  = d_in[14];
    const void* be1 = d_in[15];
    const void* g2  = d_in[16];
    const void* be2 = d_in[17];

    const size_t NE = (size_t)8 * 1024 * 512;
    char* base = (char*)d_ws;
    int*      flag    = (int*)base;                         // 256 B
    ushort_t* WqkvT   = (ushort_t*)(base + 256);            // 1.5 MB
    ushort_t* WoT     = (ushort_t*)(base + 1573120);        // 0.5 MB
    ushort_t* W1T     = (ushort_t*)(base + 2097408);        // 2 MB
    ushort_t* W2T     = (ushort_t*)(base + 4194560);        // 2 MB
    float*    biasbuf = (float*)(base + 6291712);           // 18 KB
    ushort_t* B123    = (ushort_t*)(base + 8388608);        // 24 MB  QKV (stride 1536)
    ushort_t* B4      = (ushort_t*)(base + 33554432);       // 8 MB   ATT out
    ushort_t* B0      = (ushort_t*)(base + 41943040);       // 8 MB   X / Y
    float*    R       = (float*)(base + 50331648);          // 16 MB  fp32 residual (48-64 MB)
    ushort_t* VT      = (ushort_t*)R;                       // 8 MB, dead before Wo-GEMM writes R
    ushort_t* F1      = B123;                               // 32 MB spans B123+B4
    const bool bigws  = ws_size >= (size_t)84 * 1024 * 1024;
    float*    R2      = bigws ? (float*)(base + 67108864) : R;  // 16 MB (64-80 MB)

    dim3 blk(256);
    dim3 gQKV(12, 64, 1);
    dim3 gF(16, 64, 1);
    dim3 gD1(4, 64, 1);
    dim3 gD2(4, 64, 2);

    detect_kernel<<<1, blk, 0, stream>>>((const ushort_t*)x, flag);
    pe_kernel<<<NE / 256, blk, 0, stream>>>(x, B0, flag);
    for (int l = 0; l < 4; ++l) {
        const size_t wD = (size_t)l * 512 * 512;
        const size_t wF = (size_t)l * 512 * 2048;
        const size_t bD = (size_t)l * 512;
        const size_t bF = (size_t)l * 2048;

        pack_kernel<<<3090, blk, 0, stream>>>(Wq, Wk, Wv, Wo, W1, W2,
                                              bq, bk, bv, bo, b1, b2,
                                              wD, wF, bD, bF,
                                              WqkvT, WoT, W1T, W2T, biasbuf, flag);
        gemm2_kernel<ushort_t, false><<<gQKV, blk, 0, stream>>>(B0, WqkvT, biasbuf, B123, B123, 8192, 512, 1536, 512);
        vt_kernel<<<dim3(16, 8, 8), blk, 0, stream>>>(B123, VT);
        fattn_kernel<<<dim3(8, 8, 8), blk, 0, stream>>>(B123, VT, lens, B4);
        if (bigws) {
            gemm2_kernel<float, false><<<gD2, blk, 0, stream>>>(B4, WoT, biasbuf + 1536, R, R2, 8192, 512, 512, 256);
            ln2_kernel<<<8192, blk, 0, stream>>>(B0, R, R2, g1, be1, bD, B0, flag);
            gemm2_kernel<ushort_t, true><<<gF, blk, 0, stream>>>(B0, W1T, biasbuf + 2048, F1, F1, 8192, 512, 2048, 512);
            gemm2_kernel<float, false><<<gD2, blk, 0, stream>>>(F1, W2T, biasbuf + 4096, R, R2, 8192, 2048, 512, 1024);
            ln2_kernel<<<8192, blk, 0, stream>>>(B0, R, R2, g2, be2, bD, B0, flag);
        } else {
            gemm2_kernel<float, false><<<gD1, blk, 0, stream>>>(B4, WoT, biasbuf + 1536, R, R, 8192, 512, 512, 512);
            ln_kernel<<<8192, blk, 0, stream>>>(B0, R, g1, be1, bD, B0, flag);
            gemm2_kernel<ushort_t, true><<<gF, blk, 0, stream>>>(B0, W1T, biasbuf + 2048, F1, F1, 8192, 512, 2048, 512);
            gemm2_kernel<float, false><<<gD1, blk, 0, stream>>>(F1, W2T, biasbuf + 4096, R, R, 8192, 2048, 512, 2048);
            ln_kernel<<<8192, blk, 0, stream>>>(B0, R, g2, be2, bD, B0, flag);
        }
    }
    out_kernel<<<NE / 256, blk, 0, stream>>>(B0, d_out, flag);
}